// Round 21
// baseline (111.458 us; speedup 1.0000x reference)
//
#include <hip/hip_runtime.h>

typedef __attribute__((ext_vector_type(8))) short short8;
typedef __attribute__((ext_vector_type(8))) unsigned short ushort8;
typedef __attribute__((ext_vector_type(4))) float f32x4;
typedef unsigned short u16;
typedef unsigned int u32;
typedef __attribute__((address_space(1))) const u32 gu32;
typedef __attribute__((address_space(3))) u32 lu32;

// ---------- bf16 helpers ----------
__device__ __forceinline__ u16 f2bf(float f){
  unsigned u = __float_as_uint(f);
  u += 0x7FFF + ((u >> 16) & 1);          // round-to-nearest-even
  return (u16)(u >> 16);
}
__device__ __forceinline__ float bf2f(u16 h){ return __uint_as_float(((unsigned)h) << 16); }

// ---------- problem constants ----------
#define BB   16
#define NN   1024
#define DML  512
#define DL   256
#define DM   128
#define NC   10
#define SK   140
#define KTOT (NN*DM)          // 131072

// ---------- K_prep: pack weights | W_final -> bf16 [k][c] | idx -> u16 padded ----------
__global__ void k_prep(const float* __restrict__ Wlin, const float* __restrict__ Wq,
                       const float* __restrict__ Wk, const float* __restrict__ Wv,
                       const float* __restrict__ Wadd,
                       u16* __restrict__ wlinT, u16* __restrict__ w4T,
                       const float* __restrict__ Wf, u16* __restrict__ wf2,
                       const int* __restrict__ idxs, u16* __restrict__ idxp){
  int blk = blockIdx.x, t = threadIdx.x;
  if (blk < 512){
    int id = blk*256 + t;              // 131072
    {
      int j = id >> 9;        // 0..255  (DL)
      int k = id & 511;       // 0..511  (DML)
      wlinT[id] = f2bf(Wlin[k*DL + j]);
    }
    {
      int j = id >> 8;        // 0..511  (4*DM)
      int k = id & 255;       // 0..255  (DL)
      const float* src = (j < 128) ? Wq : (j < 256) ? Wk : (j < 384) ? Wv : Wadd;
      int jj = j & 127;
      w4T[id] = f2bf(src[k*DM + jj]);
    }
  } else if (blk < 1792){
    // W_final is already [k][c] row-major: pure f32->bf16 convert, vectorized
    int i4 = (blk-512)*256 + t;        // 327,680 float4s  (1,310,720 elems)
    float4 v = ((const float4*)Wf)[i4];
    ushort4 o; o.x=f2bf(v.x); o.y=f2bf(v.y); o.z=f2bf(v.z); o.w=f2bf(v.w);
    ((ushort4*)wf2)[i4] = o;
  } else {
    int id = (blk-1792)*256 + t;       // 147456 : 1024 rows x 144 padded
    int l = id / 144;
    int s = id - l*144;
    idxp[id] = (s < SK) ? (u16)idxs[l*SK + s] : (u16)0xFFFF;
  }
}

// ---------- GEMM staging helpers (128-row tiles, BK=64) ----------
__device__ __forceinline__ void stage2(const u16* __restrict__ A, const u16* __restrict__ B,
                                       int K, int m0, int n0, int kb,
                                       u16* sA, u16* sB, int tid, int wave){
  #pragma unroll
  for (int i = 0; i < 4; ++i){
    int ci  = i*256 + tid;
    int row = ci >> 3;
    int kc  = (ci & 7) ^ (row & 7);
    __builtin_amdgcn_global_load_lds((gu32*)(A + (long)(m0+row)*K + kb + kc*8),
                                     (lu32*)(sA + (i*256 + wave*64)*8), 16, 0, 0);
    __builtin_amdgcn_global_load_lds((gu32*)(B + (long)(n0+row)*K + kb + kc*8),
                                     (lu32*)(sB + (i*256 + wave*64)*8), 16, 0, 0);
  }
}
// MFMA over one 64-wide K tile (128x128 tile, 4 waves of 64x64)
__device__ __forceinline__ void compute64(const u16* sA, const u16* sB,
                                          int lane, int wrow, int wcol, f32x4 acc[4][4]){
  #pragma unroll
  for (int kk = 0; kk < 2; ++kk){
    short8 af[4], bfr[4];
    int cb = kk*4 + (lane >> 4);
    #pragma unroll
    for (int m_=0; m_<4; ++m_){
      int row = wrow + m_*16 + (lane & 15);
      af[m_] = *(const short8*)&sA[row*64 + ((cb ^ (row & 7)) << 3)];
    }
    #pragma unroll
    for (int n_=0; n_<4; ++n_){
      int row = wcol + n_*16 + (lane & 15);
      bfr[n_] = *(const short8*)&sB[row*64 + ((cb ^ (row & 7)) << 3)];
    }
    #pragma unroll
    for (int m_=0; m_<4; ++m_)
      #pragma unroll
      for (int n_=0; n_<4; ++n_)
        acc[m_][n_] = __builtin_amdgcn_mfma_f32_16x16x32_bf16(af[m_], bfr[n_], acc[m_][n_], 0, 0, 0);
  }
}

// ---------- K2: x = emb(f32) @ W_lin + b_lin -> bf16 ; BM=64 x BN=128, coalesced epilogue ----------
__global__ __launch_bounds__(256) void k_gemm_x(const float* __restrict__ A, const u16* __restrict__ B,
                                                const float* __restrict__ bias, u16* __restrict__ out){
  __shared__ u16 smem[12288];   // 24KB: sA = [0,4096), sB = [4096,12288)
  u16* sA = smem;
  u16* sB = smem + 4096;
  const int tid  = threadIdx.x;
  const int lane = tid & 63;
  const int wave = tid >> 6;
  const int wrow = (wave >> 1) * 32;
  const int wcol = (wave & 1) * 64;
  int m0 = blockIdx.x*64, n0 = blockIdx.y*128;
  f32x4 acc[2][4];
  f32x4 z = {0.f,0.f,0.f,0.f};
  #pragma unroll
  for (int m_=0;m_<2;++m_) for (int n_=0;n_<4;++n_) acc[m_][n_] = z;

  f32x4 ra[4];      // A: 16 f32 per thread (row = tid>>2, two chunks kc=aq*2, aq*2+1)
  short8 rb[4];     // B: 4 chunks per thread
  const int arow = tid >> 2, aq = tid & 3;

  // prologue: tile 0
  {
    const float* src = A + (long)(m0+arow)*DML + aq*16;
    ra[0] = ((const f32x4*)src)[0]; ra[1] = ((const f32x4*)src)[1];
    ra[2] = ((const f32x4*)src)[2]; ra[3] = ((const f32x4*)src)[3];
    #pragma unroll
    for (int i=0;i<4;++i){
      int ci = i*256 + tid, row = ci>>3, kc = ci&7;
      rb[i] = *(const short8*)(B + (long)(n0+row)*DML + kc*8);
    }
  }
  {
    short8 o0, o1;
    #pragma unroll
    for (int j=0;j<4;++j){ o0[j]=(short)f2bf(ra[0][j]); o0[4+j]=(short)f2bf(ra[1][j]);
                           o1[j]=(short)f2bf(ra[2][j]); o1[4+j]=(short)f2bf(ra[3][j]); }
    int kc0 = aq*2, kc1 = aq*2+1;
    *(short8*)&sA[arow*64 + ((kc0 ^ (arow&7))<<3)] = o0;
    *(short8*)&sA[arow*64 + ((kc1 ^ (arow&7))<<3)] = o1;
    #pragma unroll
    for (int i=0;i<4;++i){
      int ci = i*256 + tid, row = ci>>3, kc = ci&7;
      *(short8*)&sB[row*64 + ((kc ^ (row&7))<<3)] = rb[i];
    }
  }
  __syncthreads();

  for (int tt = 0; tt < 8; ++tt){
    if (tt < 7){
      int kb = (tt+1)*64;
      const float* src = A + (long)(m0+arow)*DML + kb + aq*16;
      ra[0] = ((const f32x4*)src)[0]; ra[1] = ((const f32x4*)src)[1];
      ra[2] = ((const f32x4*)src)[2]; ra[3] = ((const f32x4*)src)[3];
      #pragma unroll
      for (int i=0;i<4;++i){
        int ci = i*256 + tid, row = ci>>3, kc = ci&7;
        rb[i] = *(const short8*)(B + (long)(n0+row)*DML + kb + kc*8);
      }
    }
    #pragma unroll
    for (int kk = 0; kk < 2; ++kk){
      short8 af[2], bfr[4];
      int cb = kk*4 + (lane >> 4);
      #pragma unroll
      for (int m_=0; m_<2; ++m_){
        int row = wrow + m_*16 + (lane & 15);
        af[m_] = *(const short8*)&sA[row*64 + ((cb ^ (row & 7)) << 3)];
      }
      #pragma unroll
      for (int n_=0; n_<4; ++n_){
        int row = wcol + n_*16 + (lane & 15);
        bfr[n_] = *(const short8*)&sB[row*64 + ((cb ^ (row & 7)) << 3)];
      }
      #pragma unroll
      for (int m_=0; m_<2; ++m_)
        #pragma unroll
        for (int n_=0; n_<4; ++n_)
          acc[m_][n_] = __builtin_amdgcn_mfma_f32_16x16x32_bf16(af[m_], bfr[n_], acc[m_][n_], 0, 0, 0);
    }
    __syncthreads();                 // after tt=7 this guarantees all waves done reading sB
    if (tt < 7){
      short8 o0, o1;
      #pragma unroll
      for (int j=0;j<4;++j){ o0[j]=(short)f2bf(ra[0][j]); o0[4+j]=(short)f2bf(ra[1][j]);
                             o1[j]=(short)f2bf(ra[2][j]); o1[4+j]=(short)f2bf(ra[3][j]); }
      int kc0 = aq*2, kc1 = aq*2+1;
      *(short8*)&sA[arow*64 + ((kc0 ^ (arow&7))<<3)] = o0;
      *(short8*)&sA[arow*64 + ((kc1 ^ (arow&7))<<3)] = o1;
      #pragma unroll
      for (int i=0;i<4;++i){
        int ci = i*256 + tid, row = ci>>3, kc = ci&7;
        *(short8*)&sB[row*64 + ((kc ^ (row&7))<<3)] = rb[i];
      }
      __syncthreads();
    }
  }

  // C tile -> LDS (sB region, 64x128 bf16 = 16KB), then coalesced store
  u16* sC = sB;
  #pragma unroll
  for (int m_=0;m_<2;++m_)
    #pragma unroll
    for (int n_=0;n_<4;++n_)
      #pragma unroll
      for (int rr=0;rr<4;++rr){
        int row = wrow + m_*16 + (lane>>4)*4 + rr;
        int col = wcol + n_*16 + (lane & 15);
        sC[row*128 + col] = f2bf(acc[m_][n_][rr] + bias[n0 + col]);
      }
  __syncthreads();
  #pragma unroll
  for (int i = 0; i < 4; ++i){
    int ci = i*256 + tid;
    int row = ci >> 4, c = ci & 15;
    *(short8*)(out + (long)(m0+row)*DL + n0 + c*8) = *(const short8*)&sC[row*128 + c*8];
  }
}

// ---------- K3: [Q|K|V|A] = x @ [Wq|Wk|Wv|Wadd], coalesced epilogue (+ V^T emit) ----------
__global__ __launch_bounds__(256) void k_gemm_qkva(const u16* __restrict__ A, const u16* __restrict__ B,
                                                   const float* __restrict__ badd,
                                                   u16* __restrict__ oq, u16* __restrict__ ok,
                                                   u16* __restrict__ ov, u16* __restrict__ oa,
                                                   u16* __restrict__ vT){
  __shared__ u16 smem[17408];   // 34KB: stage sA [0,8192) sB [8192,16384); C tile [128][136]
  u16* sA = smem;
  u16* sB = smem + 8192;
  const int tid = threadIdx.x, lane = tid & 63, wave = tid >> 6;
  const int wrow = (wave>>1)*64, wcol = (wave&1)*64;
  f32x4 acc[4][4];
  f32x4 z = {0.f,0.f,0.f,0.f};
  #pragma unroll
  for (int m_=0;m_<4;++m_) for (int n_=0;n_<4;++n_) acc[m_][n_] = z;
  int m0 = blockIdx.x*128;
  int tn = blockIdx.y;              // 0=Q 1=K 2=V 3=A
  int n0 = tn*128;

  #pragma unroll
  for (int t = 0; t < 4; ++t){
    stage2(A, B, DL, m0, n0, t*64, sA, sB, tid, wave);
    __syncthreads();
    compute64(sA, sB, lane, wrow, wcol, acc);
    __syncthreads();
  }

  u16* dst = (tn==0) ? oq : (tn==1) ? ok : (tn==2) ? ov : oa;
  u16* sC = smem;                   // [128][136] bf16 (padded: conflict-free column reads)
  #pragma unroll
  for (int m_=0;m_<4;++m_)
    #pragma unroll
    for (int n_=0;n_<4;++n_)
      #pragma unroll
      for (int r=0;r<4;++r){
        int row = wrow + m_*16 + (lane>>4)*4 + r;
        int col = wcol + n_*16 + (lane & 15);
        float v = acc[m_][n_][r];
        if (tn == 3) v += badd[col];
        sC[row*136 + col] = f2bf(v);
      }
  __syncthreads();
  u16* db = dst + (long)m0*DM;
  #pragma unroll
  for (int i = 0; i < 8; ++i){
    int ci = i*256 + tid;
    int row = ci >> 4, c = ci & 15;
    *(short8*)(db + (long)row*DM + c*8) = *(const short8*)&sC[row*136 + c*8];
  }
  if (tn == 2){
    int b2 = m0 >> 10, l0 = m0 & 1023;
    u16* vtb = vT + (long)b2*KTOT + l0;
    #pragma unroll
    for (int i = 0; i < 8; ++i){
      int gi = i*256 + tid;
      int d = gi >> 4, mc = gi & 15;
      ushort8 o;
      #pragma unroll
      for (int j = 0; j < 8; ++j) o[j] = sC[(mc*8+j)*136 + d];
      *(ushort8*)(vtb + (long)d*NN + mc*8) = o;
    }
  }
}

// ---------- K4: S[b] = Q[b] @ K[b]^T -> bf16 + FUSED sampled max/sum partials ----------
__global__ __launch_bounds__(256) void k_gemm_s(const u16* __restrict__ Q, const u16* __restrict__ Km,
                                                u16* __restrict__ S, const u16* __restrict__ idxp,
                                                float* __restrict__ pmax, float* __restrict__ psum){
  __shared__ u16 smem[16384];     // 32KB: sA [0,8192), sB [8192,16384); reused for C tile
  u16* sA = smem;
  u16* sB = smem + 8192;
  const int tid = threadIdx.x, lane = tid & 63, wave = tid >> 6;
  const int wrow = (wave>>1)*64, wcol = (wave&1)*64;
  f32x4 acc[4][4];
  f32x4 z = {0.f,0.f,0.f,0.f};
  #pragma unroll
  for (int m_=0;m_<4;++m_) for (int n_=0;n_<4;++n_) acc[m_][n_] = z;
  int b = blockIdx.x, n0 = blockIdx.y*128, m0 = blockIdx.z*128;   // b fastest => batch pinned to XCD b%8
  const u16* A = Q  + (long)b*NN*DM;
  const u16* B = Km + (long)b*NN*DM;

  stage2(A, B, DM, m0, n0, 0, sA, sB, tid, wave);
  __syncthreads();
  compute64(sA, sB, lane, wrow, wcol, acc);
  __syncthreads();
  stage2(A, B, DM, m0, n0, 64, sA, sB, tid, wave);
  __syncthreads();
  compute64(sA, sB, lane, wrow, wcol, acc);
  __syncthreads();

  // C tile -> LDS (32KB = exactly 128x128 bf16), then coalesced store
  u16* sS = smem;
  #pragma unroll
  for (int m_=0;m_<4;++m_)
    #pragma unroll
    for (int n_=0;n_<4;++n_)
      #pragma unroll
      for (int r=0;r<4;++r){
        int row = wrow + m_*16 + (lane>>4)*4 + r;
        int col = wcol + n_*16 + (lane & 15);
        sS[row*128 + col] = f2bf(acc[m_][n_][r]);
      }
  __syncthreads();

  u16* Sb = S + (long)b*NN*NN + (long)m0*NN + n0;
  #pragma unroll
  for (int i = 0; i < 8; ++i){
    int ci = i*256 + tid;
    int row = ci >> 4, c = ci & 15;
    *(short8*)(Sb + (long)row*NN + c*8) = *(const short8*)&sS[row*128 + c*8];
  }

  // fused sampled gather from the LDS tile: 2 threads per row, 72 padded slots each
  int l = tid >> 1, h = tid & 1;
  const u16* ip = idxp + (long)(m0+l)*144 + h*72;
  float mx = -1e30f, sm = 0.f;
  #pragma unroll
  for (int j = 0; j < 9; ++j){
    ushort8 v = *(const ushort8*)(ip + j*8);
    #pragma unroll
    for (int e = 0; e < 8; ++e){
      int d = (int)v[e] - n0;
      if ((unsigned)d < 128u){
        float s = bf2f(sS[l*128 + d]);
        mx = fmaxf(mx, s); sm += s;
      }
    }
  }
  float mo = __shfl_xor(mx, 1), so = __shfl_xor(sm, 1);
  mx = fmaxf(mx, mo); sm += so;
  if (h == 0){
    int o = (b*8 + blockIdx.y)*NN + m0 + l;
    pmax[o] = mx; psum[o] = sm;
  }
}

// ---------- K6: fused rank+select (blocks 0..63: 4 per batch) | V col-mean (64..79) ----------
__global__ __launch_bounds__(256) void k_ranksel(const float* __restrict__ pmax, const float* __restrict__ psum,
                                                 const u16* __restrict__ V, float* __restrict__ vmean,
                                                 int* __restrict__ mtop, int* __restrict__ selmap){
  int blk = blockIdx.x, t = threadIdx.x;
  if (blk < 64){
    __shared__ float Ml[1024];
    int b = blk >> 2, iq = blk & 3;
    #pragma unroll
    for (int r = 0; r < 4; ++r){
      int i = t + r*256;
      float mx = -1e30f, sm = 0.f;
      #pragma unroll
      for (int nb = 0; nb < 8; ++nb){
        mx = fmaxf(mx, pmax[(b*8+nb)*NN + i]);
        sm += psum[(b*8+nb)*NN + i];
      }
      Ml[i] = mx - sm * (1.0f/1024.0f);
    }
    __syncthreads();
    int i = iq*256 + t;            // my query row
    float mi = Ml[i];
    int cnt = 0;
    for (int j = 0; j < 1024; j += 4){
      f32x4 m4 = *(const f32x4*)&Ml[j];
      cnt += (m4[0] > mi) || (m4[0] == mi && (j+0) < i);
      cnt += (m4[1] > mi) || (m4[1] == mi && (j+1) < i);
      cnt += (m4[2] > mi) || (m4[2] == mi && (j+2) < i);
      cnt += (m4[3] > mi) || (m4[3] == mi && (j+3) < i);
    }
    selmap[b*NN + i] = (cnt < SK) ? cnt : -1;
    if (cnt < SK) mtop[b*SK + cnt] = i;
  } else {
    __shared__ float red[16][128];
    int b = blk - 64;
    int d8 = t & 15, seg = t >> 4;
    const u16* Vb = V + (long)b*KTOT + seg*64*DM + d8*8;
    float acc[8] = {0,0,0,0,0,0,0,0};
    for (int l = 0; l < 64; ++l){
      short8 v = *(const short8*)(Vb + l*DM);
      #pragma unroll
      for (int j=0;j<8;++j) acc[j] += bf2f((u16)v[j]);
    }
    #pragma unroll
    for (int j=0;j<8;++j) red[seg][d8*8+j] = acc[j];
    __syncthreads();
    if (t < 128){
      float s = 0.f;
      #pragma unroll
      for (int g=0;g<16;++g) s += red[g][t];
      vmean[b*DM + t] = s * (1.0f/1024.0f);
    }
  }
}

// ---------- K9: MFMA attention, K-split x2: partial O (unnormalized) + partial Z ----------
// grid (b, ublk, ksp); each split block handles 8 of 16 V^T K-tiles.
__global__ __launch_bounds__(256) void k_attn(const u16* __restrict__ S, const u16* __restrict__ vT,
                                              const int* __restrict__ mtop,
                                              float* __restrict__ updp, float* __restrict__ zsum){
  __shared__ u16 sPt[2][16*72];   // P ping-pong, stride 72 (16B-aligned rows)
  __shared__ u16 sVt[128*64];     // V^T K-tile, 16KB
  __shared__ int   sBrow[16];
  __shared__ float sMx[16];
  __shared__ float sSum[16];
  int b = blockIdx.x, u0 = blockIdx.y*16, ksp = blockIdx.z, t = threadIdx.x;
  int lane = t & 63, wave = t >> 6;
  const float inv = 0.08838834764831845f;   // 1/sqrt(128)

  if (t < 16){
    int u = u0 + t; if (u > SK-1) u = SK-1;
    sBrow[t] = mtop[b*SK + u];
  }
  __syncthreads();
  int row = t >> 4, c = t & 15;
  const u16* Srow = S + (long)b*NN*NN + (long)sBrow[row]*NN;

  // phase 1: FULL row max (16 lanes per row) -- identical across splits
  float mx = -1e30f;
  #pragma unroll
  for (int j = 0; j < 8; ++j){
    ushort8 v = *(const ushort8*)(Srow + c*8 + j*128);
    #pragma unroll
    for (int e = 0; e < 8; ++e) mx = fmaxf(mx, bf2f((u16)v[e]));
  }
  #pragma unroll
  for (int o = 1; o < 16; o <<= 1) mx = fmaxf(mx, __shfl_xor(mx, o));
  if (c == 0) sMx[row] = mx;
  __syncthreads();
  float mxr = sMx[row] * inv;
  const u16* vTb = vT + (long)b*KTOT;      // [128][1024]

  f32x4 acc[2];
  f32x4 z = {0.f,0.f,0.f,0.f};
  acc[0] = z; acc[1] = z;
  float ps = 0.f;

  for (int ks = ksp*8; ks < ksp*8 + 8; ++ks){
    // stage V^T[:, ks*64 .. +64): linear LDS dest, XOR-preswizzled source
    #pragma unroll
    for (int i = 0; i < 4; ++i){
      int ci = i*256 + t;
      int r2 = ci >> 3;
      int kc = (ci & 7) ^ (r2 & 7);
      __builtin_amdgcn_global_load_lds((gu32*)(vTb + (long)r2*NN + ks*64 + kc*8),
                                       (lu32*)(sVt + (i*256 + wave*64)*8), 16, 0, 0);
    }
    // P tile for ks (overlaps staging latency)
    u16* sp = sPt[ks & 1];
    {
      ushort4 s4 = *(const ushort4*)(Srow + ks*64 + c*4);
      float e0 = __expf(bf2f(s4.x)*inv - mxr);
      float e1 = __expf(bf2f(s4.y)*inv - mxr);
      float e2 = __expf(bf2f(s4.z)*inv - mxr);
      float e3 = __expf(bf2f(s4.w)*inv - mxr);
      ps += e0+e1+e2+e3;
      ushort4 pw; pw.x=f2bf(e0); pw.y=f2bf(e1); pw.z=f2bf(e2); pw.w=f2bf(e3);
      *(ushort4*)&sp[row*72 + c*4] = pw;
    }
    __syncthreads();
    #pragma unroll
    for (int kk = 0; kk < 2; ++kk){
      int cb = kk*4 + (lane >> 4);
      short8 af = *(const short8*)&sp[(lane & 15)*72 + cb*8];
      #pragma unroll
      for (int n_ = 0; n_ < 2; ++n_){
        int r2 = wave*32 + n_*16 + (lane & 15);
        short8 bf_ = *(const short8*)&sVt[r2*64 + ((cb ^ (r2 & 7)) << 3)];
        acc[n_] = __builtin_amdgcn_mfma_f32_16x16x32_bf16(af, bf_, acc[n_], 0, 0, 0);
      }
    }
    __syncthreads();
  }

  // partial row sums
  #pragma unroll
  for (int o = 1; o < 16; o <<= 1) ps += __shfl_xor(ps, o);
  if (c == 0) sSum[row] = ps;
  __syncthreads();
  if (t < 16){
    int urow = u0 + t;
    if (urow < SK) zsum[(ksp*BB + b)*SK + urow] = sSum[t];
  }
  int r0 = (lane >> 4) * 4;
  float* up = updp + (long)ksp*BB*SK*DM;
  #pragma unroll
  for (int n_ = 0; n_ < 2; ++n_){
    int col = wave*32 + n_*16 + (lane & 15);
    #pragma unroll
    for (int r = 0; r < 4; ++r){
      int urow = u0 + r0 + r;
      if (urow < SK)
        up[((long)b*SK + urow)*DM + col] = acc[n_][r];
    }
  }
}

// ---------- K11: final GEMV partials: (ctx+A) @ W_final ; combines K-split partials ----------
__global__ __launch_bounds__(256) void k_final(const float* __restrict__ updp, const float* __restrict__ zsum,
                                               const float* __restrict__ vmean,
                                               const int* __restrict__ selmap,
                                               const u16* __restrict__ Aad,
                                               const u16* __restrict__ wf2, float* __restrict__ part){
  __shared__ float rzs[SK];
  int b = blockIdx.x, ch = blockIdx.y, t = threadIdx.x;
  for (int i = t; i < SK; i += 256)
    rzs[i] = 1.0f / (zsum[b*SK + i] + zsum[(BB + b)*SK + i]);
  __syncthreads();
  long base = (long)b * KTOT;
  const float* up0 = updp;
  const float* up1 = updp + (long)BB*SK*DM;
  int k0 = ch * 4096;
  float acc[NC] = {0.f};
  for (int k = k0 + t; k < k0 + 4096; k += 256){
    int l = k >> 7, d = k & 127;
    int sel = selmap[b*NN + l];
    float c;
    if (sel >= 0){
      long ui = ((long)b*SK + sel)*DM + d;
      c = (up0[ui] + up1[ui]) * rzs[sel];
    } else {
      c = vmean[b*DM + d];
    }
    float v = c + bf2f(Aad[base + k]);
    const u32* w32 = (const u32*)(wf2 + (long)k*NC);   // 10 bf16 = 20B contiguous
    #pragma unroll
    for (int cc = 0; cc < 5; ++cc){
      u32 w = w32[cc];
      acc[2*cc]   += v * bf2f((u16)(w & 0xFFFF));
      acc[2*cc+1] += v * bf2f((u16)(w >> 16));
    }
  }
  __shared__ float lred[40];
  int lane = t & 63, wave = t >> 6;
  #pragma unroll
  for (int c = 0; c < NC; ++c){
    float v = acc[c];
    #pragma unroll
    for (int o=32;o;o>>=1) v += __shfl_xor(v,o);
    if (lane == 0) lred[wave*NC + c] = v;
  }
  __syncthreads();
  if (t < NC) part[(b*32 + ch)*NC + t] = lred[t] + lred[NC+t] + lred[2*NC+t] + lred[3*NC+t];
}

// ---------- K12: reduce partials + bias -> out ----------
__global__ void k_out(const float* __restrict__ part, const float* __restrict__ bfin, float* __restrict__ out){
  int t = threadIdx.x;
  if (t < BB*NC){
    int b = t / NC, c = t % NC;
    float s = bfin[c];
    #pragma unroll
    for (int ch = 0; ch < 32; ++ch) s += part[(b*32 + ch)*NC + c];
    out[t] = s;
  }
}

// ---------- launch ----------
extern "C" void kernel_launch(void* const* d_in, const int* in_sizes, int n_in,
                              void* d_out, int out_size, void* d_ws, size_t ws_size,
                              hipStream_t stream){
  const float* emb  = (const float*)d_in[0];
  const int*   idxs = (const int*)  d_in[1];
  const float* Wlin = (const float*)d_in[2];
  const float* blin = (const float*)d_in[3];
  const float* Wq   = (const float*)d_in[4];
  const float* Wk   = (const float*)d_in[5];
  const float* Wv   = (const float*)d_in[6];
  const float* Wadd = (const float*)d_in[7];
  const float* badd = (const float*)d_in[8];
  const float* Wfin = (const float*)d_in[9];
  const float* bfin = (const float*)d_in[10];
  float* out = (float*)d_out;

  char* p = (char*)d_ws;
  auto alloc = [&](size_t bytes)->char*{ char* r = p; p += (bytes + 255) & ~(size_t)255; return r; };
  u16*   wlinT  = (u16*)  alloc((size_t)DL*DML*2);
  u16*   w4T    = (u16*)  alloc((size_t)4*DM*DL*2);
  u16*   x_bf   = (u16*)  alloc((size_t)BB*NN*DL*2);
  u16*   q_bf   = (u16*)  alloc((size_t)BB*NN*DM*2);
  u16*   k_bf   = (u16*)  alloc((size_t)BB*NN*DM*2);
  u16*   v_bf   = (u16*)  alloc((size_t)BB*NN*DM*2);
  u16*   a_bf   = (u16*)  alloc((size_t)BB*NN*DM*2);
  u16*   vT     = (u16*)  alloc((size_t)BB*KTOT*2);
  u16*   s_bf   = (u16*)  alloc((size_t)BB*NN*NN*2);
  u16*   idxp   = (u16*)  alloc((size_t)NN*144*2);
  float* pmax   = (float*)alloc((size_t)BB*8*NN*4);
  float* psum   = (float*)alloc((size_t)BB*8*NN*4);
  int*   mtop   = (int*)  alloc((size_t)BB*SK*4);
  int*   selmap = (int*)  alloc((size_t)BB*NN*4);
  float* vmean  = (float*)alloc((size_t)BB*DM*4);
  float* updp   = (float*)alloc((size_t)2*BB*SK*DM*4);
  float* zsum   = (float*)alloc((size_t)2*BB*SK*4);
  u16*   wf2    = (u16*)  alloc((size_t)KTOT*NC*2);
  float* part   = (float*)alloc((size_t)BB*32*NC*4);

  // 1: pack weights + wf2 + idxp
  k_prep<<<dim3(2368), dim3(256), 0, stream>>>(Wlin, Wq, Wk, Wv, Wadd, wlinT, w4T, Wfin, wf2, idxs, idxp);
  // 2: x = emb @ Wlin + b  (BN=128 split, coalesced epilogue)
  k_gemm_x<<<dim3(256, 2), dim3(256), 0, stream>>>(emb, wlinT, blin, x_bf);
  // 3: Q,K,V,A (34KB single-buffer, coalesced epilogue; V^T emitted)
  k_gemm_qkva<<<dim3(128, 4), dim3(256), 0, stream>>>(x_bf, w4T, badd, q_bf, k_bf, v_bf, a_bf, vT);
  // 4: S = Q K^T -> bf16 + fused sampled max/sum partials (b-fastest grid)
  k_gemm_s<<<dim3(16, 8, 8), dim3(256), 0, stream>>>(q_bf, k_bf, s_bf, idxp, pmax, psum);
  // 5: fused rank+select (full-rank per block, no partials) + vmean
  k_ranksel<<<dim3(80), dim3(256), 0, stream>>>(pmax, psum, v_bf, vmean, mtop, selmap);
  // 6: MFMA attention, K-split x2 -> partial O + partial Z (288 blocks)
  k_attn<<<dim3(BB, 9, 2), dim3(256), 0, stream>>>(s_bf, vT, mtop, updp, zsum);
  // 7/8: final projection (combines split partials)
  k_final<<<dim3(BB, 32), dim3(256), 0, stream>>>(updp, zsum, vmean, selmap, a_bf, wf2, part);
  k_out<<<dim3(1), dim3(256), 0, stream>>>(part, bfin, out);
}

// Round 22
// 94.876 us; speedup vs baseline: 1.1748x; 1.1748x over previous
//
#include <hip/hip_runtime.h>

typedef __attribute__((ext_vector_type(8))) short short8;
typedef __attribute__((ext_vector_type(8))) unsigned short ushort8;
typedef __attribute__((ext_vector_type(4))) float f32x4;
typedef unsigned short u16;
typedef unsigned int u32;
typedef __attribute__((address_space(1))) const u32 gu32;
typedef __attribute__((address_space(3))) u32 lu32;

// ---------- bf16 helpers ----------
__device__ __forceinline__ u16 f2bf(float f){
  unsigned u = __float_as_uint(f);
  u += 0x7FFF + ((u >> 16) & 1);          // round-to-nearest-even
  return (u16)(u >> 16);
}
__device__ __forceinline__ float bf2f(u16 h){ return __uint_as_float(((unsigned)h) << 16); }

// ---------- problem constants ----------
#define BB   16
#define NN   1024
#define DML  512
#define DL   256
#define DM   128
#define NC   10
#define SK   140
#define KTOT (NN*DM)          // 131072

// ---------- K_prep: pack weights | W_final -> bf16 [k][c] | idx -> u16 padded ----------
__global__ void k_prep(const float* __restrict__ Wlin, const float* __restrict__ Wq,
                       const float* __restrict__ Wk, const float* __restrict__ Wv,
                       const float* __restrict__ Wadd,
                       u16* __restrict__ wlinT, u16* __restrict__ w4T,
                       const float* __restrict__ Wf, u16* __restrict__ wf2,
                       const int* __restrict__ idxs, u16* __restrict__ idxp){
  int blk = blockIdx.x, t = threadIdx.x;
  if (blk < 512){
    int id = blk*256 + t;              // 131072
    {
      int j = id >> 9;        // 0..255  (DL)
      int k = id & 511;       // 0..511  (DML)
      wlinT[id] = f2bf(Wlin[k*DL + j]);
    }
    {
      int j = id >> 8;        // 0..511  (4*DM)
      int k = id & 255;       // 0..255  (DL)
      const float* src = (j < 128) ? Wq : (j < 256) ? Wk : (j < 384) ? Wv : Wadd;
      int jj = j & 127;
      w4T[id] = f2bf(src[k*DM + jj]);
    }
  } else if (blk < 1792){
    // W_final is already [k][c] row-major: pure f32->bf16 convert, vectorized
    int i4 = (blk-512)*256 + t;        // 327,680 float4s  (1,310,720 elems)
    float4 v = ((const float4*)Wf)[i4];
    ushort4 o; o.x=f2bf(v.x); o.y=f2bf(v.y); o.z=f2bf(v.z); o.w=f2bf(v.w);
    ((ushort4*)wf2)[i4] = o;
  } else {
    int id = (blk-1792)*256 + t;       // 147456 : 1024 rows x 144 padded
    int l = id / 144;
    int s = id - l*144;
    idxp[id] = (s < SK) ? (u16)idxs[l*SK + s] : (u16)0xFFFF;
  }
}

// ---------- GEMM staging helpers (128-row tiles, BK=64) ----------
__device__ __forceinline__ void stage2(const u16* __restrict__ A, const u16* __restrict__ B,
                                       int K, int m0, int n0, int kb,
                                       u16* sA, u16* sB, int tid, int wave){
  #pragma unroll
  for (int i = 0; i < 4; ++i){
    int ci  = i*256 + tid;
    int row = ci >> 3;
    int kc  = (ci & 7) ^ (row & 7);
    __builtin_amdgcn_global_load_lds((gu32*)(A + (long)(m0+row)*K + kb + kc*8),
                                     (lu32*)(sA + (i*256 + wave*64)*8), 16, 0, 0);
    __builtin_amdgcn_global_load_lds((gu32*)(B + (long)(n0+row)*K + kb + kc*8),
                                     (lu32*)(sB + (i*256 + wave*64)*8), 16, 0, 0);
  }
}
// MFMA over one 64-wide K tile (128x128 tile, 4 waves of 64x64)
__device__ __forceinline__ void compute64(const u16* sA, const u16* sB,
                                          int lane, int wrow, int wcol, f32x4 acc[4][4]){
  #pragma unroll
  for (int kk = 0; kk < 2; ++kk){
    short8 af[4], bfr[4];
    int cb = kk*4 + (lane >> 4);
    #pragma unroll
    for (int m_=0; m_<4; ++m_){
      int row = wrow + m_*16 + (lane & 15);
      af[m_] = *(const short8*)&sA[row*64 + ((cb ^ (row & 7)) << 3)];
    }
    #pragma unroll
    for (int n_=0; n_<4; ++n_){
      int row = wcol + n_*16 + (lane & 15);
      bfr[n_] = *(const short8*)&sB[row*64 + ((cb ^ (row & 7)) << 3)];
    }
    #pragma unroll
    for (int m_=0; m_<4; ++m_)
      #pragma unroll
      for (int n_=0; n_<4; ++n_)
        acc[m_][n_] = __builtin_amdgcn_mfma_f32_16x16x32_bf16(af[m_], bfr[n_], acc[m_][n_], 0, 0, 0);
  }
}

// ---------- K2: x = emb(f32) @ W_lin + b_lin -> bf16 ; BM=64 x BN=128, coalesced epilogue ----------
__global__ __launch_bounds__(256) void k_gemm_x(const float* __restrict__ A, const u16* __restrict__ B,
                                                const float* __restrict__ bias, u16* __restrict__ out){
  __shared__ u16 smem[12288];   // 24KB: sA = [0,4096), sB = [4096,12288)
  u16* sA = smem;
  u16* sB = smem + 4096;
  const int tid  = threadIdx.x;
  const int lane = tid & 63;
  const int wave = tid >> 6;
  const int wrow = (wave >> 1) * 32;
  const int wcol = (wave & 1) * 64;
  int m0 = blockIdx.x*64, n0 = blockIdx.y*128;
  f32x4 acc[2][4];
  f32x4 z = {0.f,0.f,0.f,0.f};
  #pragma unroll
  for (int m_=0;m_<2;++m_) for (int n_=0;n_<4;++n_) acc[m_][n_] = z;

  f32x4 ra[4];      // A: 16 f32 per thread (row = tid>>2, two chunks kc=aq*2, aq*2+1)
  short8 rb[4];     // B: 4 chunks per thread
  const int arow = tid >> 2, aq = tid & 3;

  // prologue: tile 0
  {
    const float* src = A + (long)(m0+arow)*DML + aq*16;
    ra[0] = ((const f32x4*)src)[0]; ra[1] = ((const f32x4*)src)[1];
    ra[2] = ((const f32x4*)src)[2]; ra[3] = ((const f32x4*)src)[3];
    #pragma unroll
    for (int i=0;i<4;++i){
      int ci = i*256 + tid, row = ci>>3, kc = ci&7;
      rb[i] = *(const short8*)(B + (long)(n0+row)*DML + kc*8);
    }
  }
  {
    short8 o0, o1;
    #pragma unroll
    for (int j=0;j<4;++j){ o0[j]=(short)f2bf(ra[0][j]); o0[4+j]=(short)f2bf(ra[1][j]);
                           o1[j]=(short)f2bf(ra[2][j]); o1[4+j]=(short)f2bf(ra[3][j]); }
    int kc0 = aq*2, kc1 = aq*2+1;
    *(short8*)&sA[arow*64 + ((kc0 ^ (arow&7))<<3)] = o0;
    *(short8*)&sA[arow*64 + ((kc1 ^ (arow&7))<<3)] = o1;
    #pragma unroll
    for (int i=0;i<4;++i){
      int ci = i*256 + tid, row = ci>>3, kc = ci&7;
      *(short8*)&sB[row*64 + ((kc ^ (row&7))<<3)] = rb[i];
    }
  }
  __syncthreads();

  for (int tt = 0; tt < 8; ++tt){
    if (tt < 7){
      int kb = (tt+1)*64;
      const float* src = A + (long)(m0+arow)*DML + kb + aq*16;
      ra[0] = ((const f32x4*)src)[0]; ra[1] = ((const f32x4*)src)[1];
      ra[2] = ((const f32x4*)src)[2]; ra[3] = ((const f32x4*)src)[3];
      #pragma unroll
      for (int i=0;i<4;++i){
        int ci = i*256 + tid, row = ci>>3, kc = ci&7;
        rb[i] = *(const short8*)(B + (long)(n0+row)*DML + kb + kc*8);
      }
    }
    #pragma unroll
    for (int kk = 0; kk < 2; ++kk){
      short8 af[2], bfr[4];
      int cb = kk*4 + (lane >> 4);
      #pragma unroll
      for (int m_=0; m_<2; ++m_){
        int row = wrow + m_*16 + (lane & 15);
        af[m_] = *(const short8*)&sA[row*64 + ((cb ^ (row & 7)) << 3)];
      }
      #pragma unroll
      for (int n_=0; n_<4; ++n_){
        int row = wcol + n_*16 + (lane & 15);
        bfr[n_] = *(const short8*)&sB[row*64 + ((cb ^ (row & 7)) << 3)];
      }
      #pragma unroll
      for (int m_=0; m_<2; ++m_)
        #pragma unroll
        for (int n_=0; n_<4; ++n_)
          acc[m_][n_] = __builtin_amdgcn_mfma_f32_16x16x32_bf16(af[m_], bfr[n_], acc[m_][n_], 0, 0, 0);
    }
    __syncthreads();                 // after tt=7 this guarantees all waves done reading sB
    if (tt < 7){
      short8 o0, o1;
      #pragma unroll
      for (int j=0;j<4;++j){ o0[j]=(short)f2bf(ra[0][j]); o0[4+j]=(short)f2bf(ra[1][j]);
                             o1[j]=(short)f2bf(ra[2][j]); o1[4+j]=(short)f2bf(ra[3][j]); }
      int kc0 = aq*2, kc1 = aq*2+1;
      *(short8*)&sA[arow*64 + ((kc0 ^ (arow&7))<<3)] = o0;
      *(short8*)&sA[arow*64 + ((kc1 ^ (arow&7))<<3)] = o1;
      #pragma unroll
      for (int i=0;i<4;++i){
        int ci = i*256 + tid, row = ci>>3, kc = ci&7;
        *(short8*)&sB[row*64 + ((kc ^ (row&7))<<3)] = rb[i];
      }
      __syncthreads();
    }
  }

  // C tile -> LDS (sB region, 64x128 bf16 = 16KB), then coalesced store
  u16* sC = sB;
  #pragma unroll
  for (int m_=0;m_<2;++m_)
    #pragma unroll
    for (int n_=0;n_<4;++n_)
      #pragma unroll
      for (int rr=0;rr<4;++rr){
        int row = wrow + m_*16 + (lane>>4)*4 + rr;
        int col = wcol + n_*16 + (lane & 15);
        sC[row*128 + col] = f2bf(acc[m_][n_][rr] + bias[n0 + col]);
      }
  __syncthreads();
  #pragma unroll
  for (int i = 0; i < 4; ++i){
    int ci = i*256 + tid;
    int row = ci >> 4, c = ci & 15;
    *(short8*)(out + (long)(m0+row)*DL + n0 + c*8) = *(const short8*)&sC[row*128 + c*8];
  }
}

// ---------- K3: [Q|K|V|A] = x @ [Wq|Wk|Wv|Wadd], coalesced epilogue (+ V^T emit) ----------
__global__ __launch_bounds__(256) void k_gemm_qkva(const u16* __restrict__ A, const u16* __restrict__ B,
                                                   const float* __restrict__ badd,
                                                   u16* __restrict__ oq, u16* __restrict__ ok,
                                                   u16* __restrict__ ov, u16* __restrict__ oa,
                                                   u16* __restrict__ vT){
  __shared__ u16 smem[17408];   // 34KB: stage sA [0,8192) sB [8192,16384); C tile [128][136]
  u16* sA = smem;
  u16* sB = smem + 8192;
  const int tid = threadIdx.x, lane = tid & 63, wave = tid >> 6;
  const int wrow = (wave>>1)*64, wcol = (wave&1)*64;
  f32x4 acc[4][4];
  f32x4 z = {0.f,0.f,0.f,0.f};
  #pragma unroll
  for (int m_=0;m_<4;++m_) for (int n_=0;n_<4;++n_) acc[m_][n_] = z;
  int m0 = blockIdx.x*128;
  int tn = blockIdx.y;              // 0=Q 1=K 2=V 3=A
  int n0 = tn*128;

  #pragma unroll
  for (int t = 0; t < 4; ++t){
    stage2(A, B, DL, m0, n0, t*64, sA, sB, tid, wave);
    __syncthreads();
    compute64(sA, sB, lane, wrow, wcol, acc);
    __syncthreads();
  }

  u16* dst = (tn==0) ? oq : (tn==1) ? ok : (tn==2) ? ov : oa;
  u16* sC = smem;                   // [128][136] bf16 (padded: conflict-free column reads)
  #pragma unroll
  for (int m_=0;m_<4;++m_)
    #pragma unroll
    for (int n_=0;n_<4;++n_)
      #pragma unroll
      for (int r=0;r<4;++r){
        int row = wrow + m_*16 + (lane>>4)*4 + r;
        int col = wcol + n_*16 + (lane & 15);
        float v = acc[m_][n_][r];
        if (tn == 3) v += badd[col];
        sC[row*136 + col] = f2bf(v);
      }
  __syncthreads();
  u16* db = dst + (long)m0*DM;
  #pragma unroll
  for (int i = 0; i < 8; ++i){
    int ci = i*256 + tid;
    int row = ci >> 4, c = ci & 15;
    *(short8*)(db + (long)row*DM + c*8) = *(const short8*)&sC[row*136 + c*8];
  }
  if (tn == 2){
    int b2 = m0 >> 10, l0 = m0 & 1023;
    u16* vtb = vT + (long)b2*KTOT + l0;
    #pragma unroll
    for (int i = 0; i < 8; ++i){
      int gi = i*256 + tid;
      int d = gi >> 4, mc = gi & 15;
      ushort8 o;
      #pragma unroll
      for (int j = 0; j < 8; ++j) o[j] = sC[(mc*8+j)*136 + d];
      *(ushort8*)(vtb + (long)d*NN + mc*8) = o;
    }
  }
}

// ---------- K4: S[b] = Q[b] @ K[b]^T -> bf16 + FUSED sampled max/sum partials ----------
__global__ __launch_bounds__(256) void k_gemm_s(const u16* __restrict__ Q, const u16* __restrict__ Km,
                                                u16* __restrict__ S, const u16* __restrict__ idxp,
                                                float* __restrict__ pmax, float* __restrict__ psum){
  __shared__ u16 smem[16384];     // 32KB: sA [0,8192), sB [8192,16384); reused for C tile
  u16* sA = smem;
  u16* sB = smem + 8192;
  const int tid = threadIdx.x, lane = tid & 63, wave = tid >> 6;
  const int wrow = (wave>>1)*64, wcol = (wave&1)*64;
  f32x4 acc[4][4];
  f32x4 z = {0.f,0.f,0.f,0.f};
  #pragma unroll
  for (int m_=0;m_<4;++m_) for (int n_=0;n_<4;++n_) acc[m_][n_] = z;
  int b = blockIdx.x, n0 = blockIdx.y*128, m0 = blockIdx.z*128;   // b fastest => batch pinned to XCD b%8
  const u16* A = Q  + (long)b*NN*DM;
  const u16* B = Km + (long)b*NN*DM;

  stage2(A, B, DM, m0, n0, 0, sA, sB, tid, wave);
  __syncthreads();
  compute64(sA, sB, lane, wrow, wcol, acc);
  __syncthreads();
  stage2(A, B, DM, m0, n0, 64, sA, sB, tid, wave);
  __syncthreads();
  compute64(sA, sB, lane, wrow, wcol, acc);
  __syncthreads();

  // C tile -> LDS (32KB = exactly 128x128 bf16), then coalesced store
  u16* sS = smem;
  #pragma unroll
  for (int m_=0;m_<4;++m_)
    #pragma unroll
    for (int n_=0;n_<4;++n_)
      #pragma unroll
      for (int r=0;r<4;++r){
        int row = wrow + m_*16 + (lane>>4)*4 + r;
        int col = wcol + n_*16 + (lane & 15);
        sS[row*128 + col] = f2bf(acc[m_][n_][r]);
      }
  __syncthreads();

  u16* Sb = S + (long)b*NN*NN + (long)m0*NN + n0;
  #pragma unroll
  for (int i = 0; i < 8; ++i){
    int ci = i*256 + tid;
    int row = ci >> 4, c = ci & 15;
    *(short8*)(Sb + (long)row*NN + c*8) = *(const short8*)&sS[row*128 + c*8];
  }

  // fused sampled gather from the LDS tile: 2 threads per row, 72 padded slots each
  int l = tid >> 1, h = tid & 1;
  const u16* ip = idxp + (long)(m0+l)*144 + h*72;
  float mx = -1e30f, sm = 0.f;
  #pragma unroll
  for (int j = 0; j < 9; ++j){
    ushort8 v = *(const ushort8*)(ip + j*8);
    #pragma unroll
    for (int e = 0; e < 8; ++e){
      int d = (int)v[e] - n0;
      if ((unsigned)d < 128u){
        float s = bf2f(sS[l*128 + d]);
        mx = fmaxf(mx, s); sm += s;
      }
    }
  }
  float mo = __shfl_xor(mx, 1), so = __shfl_xor(sm, 1);
  mx = fmaxf(mx, mo); sm += so;
  if (h == 0){
    int o = (b*8 + blockIdx.y)*NN + m0 + l;
    pmax[o] = mx; psum[o] = sm;
  }
}

// ---------- K6a: M-reduce + partial ranks (blocks 0..255) | V col-mean (256..271) ----------
__global__ __launch_bounds__(256) void k_rankvm(const float* __restrict__ pmax, const float* __restrict__ psum,
                                                int* __restrict__ partial,
                                                const u16* __restrict__ V, float* __restrict__ vmean){
  int blk = blockIdx.x, t = threadIdx.x;
  if (blk < 256){
    __shared__ float Ml[1024];
    int b = blk >> 4, jc = blk & 15;
    #pragma unroll
    for (int r=0;r<4;++r){
      int i = t + r*256;
      float mx = -1e30f, sm = 0.f;
      #pragma unroll
      for (int nb=0;nb<8;++nb){
        mx = fmaxf(mx, pmax[(b*8+nb)*NN + i]);
        sm += psum[(b*8+nb)*NN + i];
      }
      Ml[i] = mx - sm * (1.0f/1024.0f);
    }
    __syncthreads();
    float mi[4];
    int cnt[4] = {0,0,0,0};
    #pragma unroll
    for (int r=0;r<4;++r) mi[r] = Ml[t + r*256];
    int j0 = jc*64;
    for (int j = 0; j < 64; ++j){
      float mj = Ml[j0 + j];
      int jg = j0 + j;
      #pragma unroll
      for (int r=0;r<4;++r){
        int i = t + r*256;
        cnt[r] += (mj > mi[r]) || (mj == mi[r] && jg < i);
      }
    }
    int* pb = partial + (b*16 + jc)*NN;
    #pragma unroll
    for (int r=0;r<4;++r) pb[t + r*256] = cnt[r];
  } else {
    __shared__ float red[16][128];
    int b = blk - 256;
    int d8 = t & 15, seg = t >> 4;
    const u16* Vb = V + (long)b*KTOT + seg*64*DM + d8*8;
    float acc[8] = {0,0,0,0,0,0,0,0};
    for (int l = 0; l < 64; ++l){
      short8 v = *(const short8*)(Vb + l*DM);
      #pragma unroll
      for (int j=0;j<8;++j) acc[j] += bf2f((u16)v[j]);
    }
    #pragma unroll
    for (int j=0;j<8;++j) red[seg][d8*8+j] = acc[j];
    __syncthreads();
    if (t < 128){
      float s = 0.f;
      #pragma unroll
      for (int g=0;g<16;++g) s += red[g][t];
      vmean[b*DM + t] = s * (1.0f/1024.0f);
    }
  }
}

// ---------- K6b: sum partial ranks -> mtop + selmap ----------
__global__ __launch_bounds__(1024) void k_sel(const int* __restrict__ partial, int* __restrict__ mtop,
                                              int* __restrict__ selmap){
  int b = blockIdx.x, i = threadIdx.x;
  int cnt = 0;
  #pragma unroll
  for (int jc = 0; jc < 16; ++jc) cnt += partial[(b*16 + jc)*NN + i];
  selmap[b*NN + i] = (cnt < SK) ? cnt : -1;
  if (cnt < SK) mtop[b*SK + cnt] = i;
}

// ---------- K9: MFMA attention, K-split x2: partial O (unnormalized) + partial Z ----------
// grid (b, ublk, ksp); each split block handles 8 of 16 V^T K-tiles.
__global__ __launch_bounds__(256) void k_attn(const u16* __restrict__ S, const u16* __restrict__ vT,
                                              const int* __restrict__ mtop,
                                              float* __restrict__ updp, float* __restrict__ zsum){
  __shared__ u16 sPt[2][16*72];   // P ping-pong, stride 72 (16B-aligned rows)
  __shared__ u16 sVt[128*64];     // V^T K-tile, 16KB
  __shared__ int   sBrow[16];
  __shared__ float sMx[16];
  __shared__ float sSum[16];
  int b = blockIdx.x, u0 = blockIdx.y*16, ksp = blockIdx.z, t = threadIdx.x;
  int lane = t & 63, wave = t >> 6;
  const float inv = 0.08838834764831845f;   // 1/sqrt(128)

  if (t < 16){
    int u = u0 + t; if (u > SK-1) u = SK-1;
    sBrow[t] = mtop[b*SK + u];
  }
  __syncthreads();
  int row = t >> 4, c = t & 15;
  const u16* Srow = S + (long)b*NN*NN + (long)sBrow[row]*NN;

  // phase 1: FULL row max (16 lanes per row) -- identical across splits
  float mx = -1e30f;
  #pragma unroll
  for (int j = 0; j < 8; ++j){
    ushort8 v = *(const ushort8*)(Srow + c*8 + j*128);
    #pragma unroll
    for (int e = 0; e < 8; ++e) mx = fmaxf(mx, bf2f((u16)v[e]));
  }
  #pragma unroll
  for (int o = 1; o < 16; o <<= 1) mx = fmaxf(mx, __shfl_xor(mx, o));
  if (c == 0) sMx[row] = mx;
  __syncthreads();
  float mxr = sMx[row] * inv;
  const u16* vTb = vT + (long)b*KTOT;      // [128][1024]

  f32x4 acc[2];
  f32x4 z = {0.f,0.f,0.f,0.f};
  acc[0] = z; acc[1] = z;
  float ps = 0.f;

  for (int ks = ksp*8; ks < ksp*8 + 8; ++ks){
    // stage V^T[:, ks*64 .. +64): linear LDS dest, XOR-preswizzled source
    #pragma unroll
    for (int i = 0; i < 4; ++i){
      int ci = i*256 + t;
      int r2 = ci >> 3;
      int kc = (ci & 7) ^ (r2 & 7);
      __builtin_amdgcn_global_load_lds((gu32*)(vTb + (long)r2*NN + ks*64 + kc*8),
                                       (lu32*)(sVt + (i*256 + wave*64)*8), 16, 0, 0);
    }
    // P tile for ks (overlaps staging latency)
    u16* sp = sPt[ks & 1];
    {
      ushort4 s4 = *(const ushort4*)(Srow + ks*64 + c*4);
      float e0 = __expf(bf2f(s4.x)*inv - mxr);
      float e1 = __expf(bf2f(s4.y)*inv - mxr);
      float e2 = __expf(bf2f(s4.z)*inv - mxr);
      float e3 = __expf(bf2f(s4.w)*inv - mxr);
      ps += e0+e1+e2+e3;
      ushort4 pw; pw.x=f2bf(e0); pw.y=f2bf(e1); pw.z=f2bf(e2); pw.w=f2bf(e3);
      *(ushort4*)&sp[row*72 + c*4] = pw;
    }
    __syncthreads();
    #pragma unroll
    for (int kk = 0; kk < 2; ++kk){
      int cb = kk*4 + (lane >> 4);
      short8 af = *(const short8*)&sp[(lane & 15)*72 + cb*8];
      #pragma unroll
      for (int n_ = 0; n_ < 2; ++n_){
        int r2 = wave*32 + n_*16 + (lane & 15);
        short8 bf_ = *(const short8*)&sVt[r2*64 + ((cb ^ (r2 & 7)) << 3)];
        acc[n_] = __builtin_amdgcn_mfma_f32_16x16x32_bf16(af, bf_, acc[n_], 0, 0, 0);
      }
    }
    __syncthreads();
  }

  // partial row sums
  #pragma unroll
  for (int o = 1; o < 16; o <<= 1) ps += __shfl_xor(ps, o);
  if (c == 0) sSum[row] = ps;
  __syncthreads();
  if (t < 16){
    int urow = u0 + t;
    if (urow < SK) zsum[(ksp*BB + b)*SK + urow] = sSum[t];
  }
  int r0 = (lane >> 4) * 4;
  float* up = updp + (long)ksp*BB*SK*DM;
  #pragma unroll
  for (int n_ = 0; n_ < 2; ++n_){
    int col = wave*32 + n_*16 + (lane & 15);
    #pragma unroll
    for (int r = 0; r < 4; ++r){
      int urow = u0 + r0 + r;
      if (urow < SK)
        up[((long)b*SK + urow)*DM + col] = acc[n_][r];
    }
  }
}

// ---------- K11: final GEMV partials: (ctx+A) @ W_final ; combines K-split partials ----------
__global__ __launch_bounds__(256) void k_final(const float* __restrict__ updp, const float* __restrict__ zsum,
                                               const float* __restrict__ vmean,
                                               const int* __restrict__ selmap,
                                               const u16* __restrict__ Aad,
                                               const u16* __restrict__ wf2, float* __restrict__ part){
  __shared__ float rzs[SK];
  int b = blockIdx.x, ch = blockIdx.y, t = threadIdx.x;
  for (int i = t; i < SK; i += 256)
    rzs[i] = 1.0f / (zsum[b*SK + i] + zsum[(BB + b)*SK + i]);
  __syncthreads();
  long base = (long)b * KTOT;
  const float* up0 = updp;
  const float* up1 = updp + (long)BB*SK*DM;
  int k0 = ch * 4096;
  float acc[NC] = {0.f};
  for (int k = k0 + t; k < k0 + 4096; k += 256){
    int l = k >> 7, d = k & 127;
    int sel = selmap[b*NN + l];
    float c;
    if (sel >= 0){
      long ui = ((long)b*SK + sel)*DM + d;
      c = (up0[ui] + up1[ui]) * rzs[sel];
    } else {
      c = vmean[b*DM + d];
    }
    float v = c + bf2f(Aad[base + k]);
    const u32* w32 = (const u32*)(wf2 + (long)k*NC);   // 10 bf16 = 20B contiguous
    #pragma unroll
    for (int cc = 0; cc < 5; ++cc){
      u32 w = w32[cc];
      acc[2*cc]   += v * bf2f((u16)(w & 0xFFFF));
      acc[2*cc+1] += v * bf2f((u16)(w >> 16));
    }
  }
  __shared__ float lred[40];
  int lane = t & 63, wave = t >> 6;
  #pragma unroll
  for (int c = 0; c < NC; ++c){
    float v = acc[c];
    #pragma unroll
    for (int o=32;o;o>>=1) v += __shfl_xor(v,o);
    if (lane == 0) lred[wave*NC + c] = v;
  }
  __syncthreads();
  if (t < NC) part[(b*32 + ch)*NC + t] = lred[t] + lred[NC+t] + lred[2*NC+t] + lred[3*NC+t];
}

// ---------- K12: reduce partials + bias -> out ----------
__global__ void k_out(const float* __restrict__ part, const float* __restrict__ bfin, float* __restrict__ out){
  int t = threadIdx.x;
  if (t < BB*NC){
    int b = t / NC, c = t % NC;
    float s = bfin[c];
    #pragma unroll
    for (int ch = 0; ch < 32; ++ch) s += part[(b*32 + ch)*NC + c];
    out[t] = s;
  }
}

// ---------- launch ----------
extern "C" void kernel_launch(void* const* d_in, const int* in_sizes, int n_in,
                              void* d_out, int out_size, void* d_ws, size_t ws_size,
                              hipStream_t stream){
  const float* emb  = (const float*)d_in[0];
  const int*   idxs = (const int*)  d_in[1];
  const float* Wlin = (const float*)d_in[2];
  const float* blin = (const float*)d_in[3];
  const float* Wq   = (const float*)d_in[4];
  const float* Wk   = (const float*)d_in[5];
  const float* Wv   = (const float*)d_in[6];
  const float* Wadd = (const float*)d_in[7];
  const float* badd = (const float*)d_in[8];
  const float* Wfin = (const float*)d_in[9];
  const float* bfin = (const float*)d_in[10];
  float* out = (float*)d_out;

  char* p = (char*)d_ws;
  auto alloc = [&](size_t bytes)->char*{ char* r = p; p += (bytes + 255) & ~(size_t)255; return r; };
  u16*   wlinT  = (u16*)  alloc((size_t)DL*DML*2);
  u16*   w4T    = (u16*)  alloc((size_t)4*DM*DL*2);
  u16*   x_bf   = (u16*)  alloc((size_t)BB*NN*DL*2);
  u16*   q_bf   = (u16*)  alloc((size_t)BB*NN*DM*2);
  u16*   k_bf   = (u16*)  alloc((size_t)BB*NN*DM*2);
  u16*   v_bf   = (u16*)  alloc((size_t)BB*NN*DM*2);
  u16*   a_bf   = (u16*)  alloc((size_t)BB*NN*DM*2);
  u16*   vT     = (u16*)  alloc((size_t)BB*KTOT*2);
  u16*   s_bf   = (u16*)  alloc((size_t)BB*NN*NN*2);
  u16*   idxp   = (u16*)  alloc((size_t)NN*144*2);
  float* pmax   = (float*)alloc((size_t)BB*8*NN*4);
  float* psum   = (float*)alloc((size_t)BB*8*NN*4);
  int*   rankp  = (int*)  alloc((size_t)BB*16*NN*4);
  int*   mtop   = (int*)  alloc((size_t)BB*SK*4);
  int*   selmap = (int*)  alloc((size_t)BB*NN*4);
  float* vmean  = (float*)alloc((size_t)BB*DM*4);
  float* updp   = (float*)alloc((size_t)2*BB*SK*DM*4);
  float* zsum   = (float*)alloc((size_t)2*BB*SK*4);
  u16*   wf2    = (u16*)  alloc((size_t)KTOT*NC*2);
  float* part   = (float*)alloc((size_t)BB*32*NC*4);

  // 1: pack weights + wf2 + idxp
  k_prep<<<dim3(2368), dim3(256), 0, stream>>>(Wlin, Wq, Wk, Wv, Wadd, wlinT, w4T, Wfin, wf2, idxs, idxp);
  // 2: x = emb @ Wlin + b  (BN=128 split, coalesced epilogue)
  k_gemm_x<<<dim3(256, 2), dim3(256), 0, stream>>>(emb, wlinT, blin, x_bf);
  // 3: Q,K,V,A (34KB single-buffer, coalesced epilogue; V^T emitted)
  k_gemm_qkva<<<dim3(128, 4), dim3(256), 0, stream>>>(x_bf, w4T, badd, q_bf, k_bf, v_bf, a_bf, vT);
  // 4: S = Q K^T -> bf16 + fused sampled max/sum partials (b-fastest grid)
  k_gemm_s<<<dim3(16, 8, 8), dim3(256), 0, stream>>>(q_bf, k_bf, s_bf, idxp, pmax, psum);
  // 5: M-reduce + partial ranks + vmean
  k_rankvm<<<dim3(272), dim3(256), 0, stream>>>(pmax, psum, rankp, v_bf, vmean);
  // 6: select top-140
  k_sel<<<dim3(BB), dim3(1024), 0, stream>>>(rankp, mtop, selmap);
  // 7: MFMA attention, K-split x2 -> partial O + partial Z (288 blocks)
  k_attn<<<dim3(BB, 9, 2), dim3(256), 0, stream>>>(s_bf, vT, mtop, updp, zsum);
  // 8/9: final projection (combines split partials)
  k_final<<<dim3(BB, 32), dim3(256), 0, stream>>>(updp, zsum, vmean, selmap, a_bf, wf2, part);
  k_out<<<dim3(1), dim3(256), 0, stream>>>(part, bfin, out);
}